// Round 8
// baseline (3705.879 us; speedup 1.0000x reference)
//
#include <hip/hip_runtime.h>
#include <stdint.h>

typedef _Float16 f16;
typedef _Float16 f16x4 __attribute__((ext_vector_type(4)));
typedef _Float16 f16x8 __attribute__((ext_vector_type(8)));
typedef float f32x4 __attribute__((ext_vector_type(4)));

#define SEQ 512
#define NB  200
#define HD  256
#define GD  768
#define BW  16
#define NBLK 13                    // ceil(200/16)
#define GI_TSTRIDE (NBLK*12288)    // halves per timestep = 159744
#define LOG2E 1.44269504f

__device__ __forceinline__ f32x4 mfma16(f16x8 a, f16x8 b, f32x4 c){
  return __builtin_amdgcn_mfma_f32_16x16x32_f16(a, b, c, 0, 0, 0);
}

// ---------------- fp32 -> fp16 convert ----------------
__global__ void cvt_f32_f16(const float* __restrict__ src, f16* __restrict__ dst, int n4){
  int i = blockIdx.x * blockDim.x + threadIdx.x;
  int stride = gridDim.x * blockDim.x;
  for (; i < n4; i += stride){
    float4 v = ((const float4*)src)[i];
    f16x4 o = { (f16)v.x, (f16)v.y, (f16)v.z, (f16)v.w };
    ((f16x4*)dst)[i] = o;
  }
}

// ---------------- GEMM: C[m][n] = sum_k A[m][k]*B[n][k] (both K-major) -------
// MODE 0: fp16 out into PERMUTED GI layout for the 16-wave gru reader.
//   Per (t, blk): 24KB region of 24 1KB chunks.
//   g -> q=g>>8, j=g&255, w=j>>4, jr=j&15, lane=(jr>>2)*16 + (b&15), rr=jr&3.
//   q<2 (r,z): idx = region + w*512 + lane*8 + q*4 + rr        (16B/lane)
//   q==2 (n):  idx = region + (16+(w>>1))*512 + (w&1)*256 + lane*4 + rr
//   bias1[g] (+bias2[g] for g<512: b_hh r,z folded in exactly).
// MODE 1: fp32 partials out[(z*512+row)*N+col].  grid (M/128, N/128, splits)
template<int MODE>
__global__ __launch_bounds__(256, 2)
void gemm_bt(const f16* __restrict__ A, const f16* __restrict__ B,
             f16* __restrict__ Cb, float* __restrict__ Cf,
             const float* __restrict__ bias1, const float* __restrict__ bias2,
             int K, int N, int klen)
{
  const int l  = threadIdx.x & 63;
  const int w  = threadIdx.x >> 6;
  const int lr = l & 15, lg = l >> 4;
  const int Mb = blockIdx.x * 128 + (w >> 1) * 64;
  const int Nb = blockIdx.y * 128 + (w & 1) * 64;
  const int kb = blockIdx.z * klen;

  const f16* Ap = A + (size_t)(Mb + lr) * K + kb + lg * 8;
  const f16* Bp = B + (size_t)(Nb + lr) * K + kb + lg * 8;

  f32x4 acc[4][4];
  #pragma unroll
  for (int i = 0; i < 4; ++i)
    #pragma unroll
    for (int j = 0; j < 4; ++j)
      acc[i][j] = (f32x4){0.f, 0.f, 0.f, 0.f};

  for (int k = 0; k < klen; k += 32){
    f16x8 af[4], bfr[4];
    #pragma unroll
    for (int i = 0; i < 4; ++i){
      af[i]  = *(const f16x8*)(Ap + (size_t)i * 16 * K + k);
      bfr[i] = *(const f16x8*)(Bp + (size_t)i * 16 * K + k);
    }
    #pragma unroll
    for (int i = 0; i < 4; ++i)
      #pragma unroll
      for (int j = 0; j < 4; ++j)
        acc[i][j] = mfma16(af[i], bfr[j], acc[i][j]);
  }

  if (MODE == 0){
    float bv[4];
    #pragma unroll
    for (int j = 0; j < 4; ++j){
      int g = Nb + j*16 + lr;
      bv[j] = bias1[g] + (g < 512 ? bias2[g] : 0.f);
    }
    #pragma unroll
    for (int i = 0; i < 4; ++i)
      #pragma unroll
      for (int r = 0; r < 4; ++r){
        int row = Mb + i*16 + lg*4 + r;
        int t = (int)(((uint64_t)(uint32_t)row * 167773u) >> 25);  // row/200 exact
        int b = row - t*200;
        int bblk = b >> 4, blr = b & 15;
        size_t region = ((size_t)t*NBLK + bblk) * 12288;
        #pragma unroll
        for (int j = 0; j < 4; ++j){
          int g = Nb + j*16 + lr;
          int q = g >> 8, jj = g & 255;
          int ww = jj >> 4, jr = jj & 15;
          int lane = (jr >> 2)*16 + blr;
          size_t idx;
          if (q < 2) idx = region + (size_t)ww*512 + lane*8 + q*4 + (jr & 3);
          else       idx = region + (size_t)(16 + (ww>>1))*512 + (ww&1)*256 + lane*4 + (jr & 3);
          Cb[idx] = (f16)(acc[i][j][r] + bv[j]);
        }
      }
  } else {
    #pragma unroll
    for (int i = 0; i < 4; ++i)
      #pragma unroll
      for (int j = 0; j < 4; ++j)
        #pragma unroll
        for (int r = 0; r < 4; ++r){
          int row = Mb + i*16 + lg*4 + r;
          int col = Nb + j*16 + lr;
          Cf[((size_t)blockIdx.z * 512 + row) * N + col] = acc[i][j][r];
        }
  }
}

// ---------------- persistent GRU layer: 13 blocks x 16 batch rows ------------
// 1024 threads = 16 waves = 4/SIMD -> hard 128-VGPR budget. Wave w owns hidden
// [16w,16w+16): weights = 3 gate tiles x 8 k-frags = 96 VGPR/lane -> FITS the
// budget (the 8-wave variant needed 192 and always rematted = L2 refetch/step).
// Pure intrinsics (no asm MFMA). h double-buffered in LDS (swizzle
// c(b)=(b^(b>>2))&3); h_old in regs. gi prefetched one step ahead via
// global_load_lds: per wave 2 chunks (its rz chunk + its n chunk, n chunks
// DMA'd by BOTH reader waves with identical bytes -> no cross-wave DMA race).
// vmcnt(0) at step top: no VMEM-ordering assumptions.
__global__
__attribute__((amdgpu_flat_work_group_size(1024, 1024)))
void gru_layer(const f16* __restrict__ whh, const float* __restrict__ bhh,
               const f16* __restrict__ gi, f16* __restrict__ hs)
{
  // [0,16384): h bufs (2x8192). [16384,65536): gi bufs (2x24576). pad -> 96KB
  // (1 block/CU).
  __shared__ __align__(16) unsigned char sm[16384 + 49152 + 32768];
  const int tid = threadIdx.x;
  const int w  = tid >> 6, l = tid & 63;
  const int lr = l & 15, lg = l >> 4;
  const int b0 = blockIdx.x * BW;
  const bool bval = (b0 + lr) < NB;

  ((int2*)sm)[tid] = make_int2(0,0);   // zero h buf0 (1024*8B = 8192)

  const int nchunk = 16 + (w >> 1);
  const f16* glane = gi + (size_t)blockIdx.x * 12288 + l*8;
#define DMA_GI(P) do { \
    __builtin_amdgcn_global_load_lds( \
        (const __attribute__((address_space(1))) void*)(glane + w*512), \
        (__attribute__((address_space(3))) void*)(sm + 16384 + (P)*24576 + w*1024), \
        16, 0, 0); \
    __builtin_amdgcn_global_load_lds( \
        (const __attribute__((address_space(1))) void*)(glane + nchunk*512), \
        (__attribute__((address_space(3))) void*)(sm + 16384 + (P)*24576 + nchunk*1024), \
        16, 0, 0); \
  } while(0)

  DMA_GI(0);   // t=0 prefetch

  // weight fragments: tile q covers gate rows q*256 + 16w + [0,16)
  // A-frag lane l: row = base + lr, k = kk*32 + lg*8 .. +7
  f16x8 wA[3][8];
  #pragma unroll
  for (int q = 0; q < 3; ++q)
    #pragma unroll
    for (int kk = 0; kk < 8; ++kk)
      wA[q][kk] = *(const f16x8*)(whh + (size_t)(q*256 + w*16 + lr)*256 + kk*32 + lg*8);

  // n-gate bias for own rows j = 16w + lg*4 + r, packed f16
  f16x4 bnv;
  {
    float4 bv = *(const float4*)(bhh + 512 + w*16 + lg*4);
    bnv = (f16x4){(f16)bv.x,(f16)bv.y,(f16)bv.z,(f16)bv.w};
  }

  // LDS addressing. h element (k,b) at byte:
  //   (k>>5)*1024 + b*64 + (((k&31)*2) ^ (c(b)<<4)),  c(b) = (b ^ (b>>2)) & 3
  const int cswz = ((lr ^ (lr >> 2)) & 3) << 4;
  const int hrd  = lr*64 + ((lg*16) ^ cswz);                    // + kk*1024 + P*8192
  const int girz = 16384 + w*1024 + l*16;                       // + P*24576
  const int gin  = 16384 + nchunk*1024 + (w&1)*512 + l*8;       // + P*24576
  const int hwb  = (w>>1)*1024 + lr*64 + ((((w&1)*32) + lg*8) ^ cswz);  // + (P^1)*8192

  f16* hp = hs + (size_t)(b0 + lr)*HD + w*16 + lg*4;
  f16x4 hvp = (f16x4){(f16)0.f,(f16)0.f,(f16)0.f,(f16)0.f};

  asm volatile("s_waitcnt vmcnt(0)" ::: "memory");  // drain prologue
  __syncthreads();

#define GRUSTEP(P) do { \
    asm volatile("s_waitcnt vmcnt(0)" ::: "memory"); /* gi DMAs landed */ \
    f16x8 rz = *(const f16x8*)(sm + (P)*24576 + girz); \
    f16x4 nn = *(const f16x4*)(sm + (P)*24576 + gin); \
    f32x4 a0 = {0.f,0.f,0.f,0.f}, a1 = {0.f,0.f,0.f,0.f}; \
    f32x4 a2 = {(float)bnv[0],(float)bnv[1],(float)bnv[2],(float)bnv[3]}; \
    glane += GI_TSTRIDE; \
    DMA_GI((P)^1); \
    _Pragma("unroll") \
    for (int kk = 0; kk < 8; ++kk){ \
      f16x8 hf = *(const f16x8*)(sm + (P)*8192 + kk*1024 + hrd); \
      a0 = mfma16(wA[0][kk], hf, a0); \
      a1 = mfma16(wA[1][kk], hf, a1); \
      a2 = mfma16(wA[2][kk], hf, a2); \
    } \
    f16x4 hv; \
    _Pragma("unroll") \
    for (int r = 0; r < 4; ++r){ \
      float rg = __builtin_amdgcn_rcpf(1.f + __builtin_amdgcn_exp2f(-LOG2E*((float)rz[r] + a0[r]))); \
      float zg = __builtin_amdgcn_rcpf(1.f + __builtin_amdgcn_exp2f(-LOG2E*((float)rz[4+r] + a1[r]))); \
      float aa = (float)nn[r] + rg*a2[r]; \
      float ng = 2.f*__builtin_amdgcn_rcpf(1.f + __builtin_amdgcn_exp2f(-2.f*LOG2E*aa)) - 1.f; \
      float h  = ng + zg*((float)hvp[r] - ng); \
      hv[r] = (f16)h; \
    } \
    hvp = hv; \
    *(f16x4*)(sm + ((P)^1)*8192 + hwb) = hv; \
    if (bval) *(f16x4*)hp = hv; \
    hp += (size_t)NB*HD; \
    asm volatile("s_waitcnt lgkmcnt(0)" ::: "memory"); \
    __builtin_amdgcn_sched_barrier(0); \
    __builtin_amdgcn_s_barrier(); \
    __builtin_amdgcn_sched_barrier(0); \
  } while(0)

  for (int th = 0; th < SEQ/2; ++th){
    GRUSTEP(0);
    GRUSTEP(1);
  }
#undef GRUSTEP
#undef DMA_GI
}

// ---------------- LayerNorm(hidden) + ReLU, in place on fp16 [rows][256] -----
// Vectorized: each 64-lane wave handles 2 rows; lane reads f16x8.
__global__ __launch_bounds__(256)
void ln_relu(f16* __restrict__ hs, const float* __restrict__ lnw,
             const float* __restrict__ lnb)
{
  const int tid = threadIdx.x;
  const int wv = tid >> 6;           // 4 waves/block
  const int lane = tid & 63;
  const int half = lane >> 5;        // row within pair
  const int c0 = (lane & 31) * 8;
  float gw[8], gb[8];
  #pragma unroll
  for (int r = 0; r < 8; ++r){ gw[r] = lnw[c0 + r]; gb[r] = lnb[c0 + r]; }
  const int npairs = SEQ * NB / 2;   // 51200
  for (int pair = blockIdx.x * 4 + wv; pair < npairs; pair += gridDim.x * 4){
    f16* p = hs + (size_t)(pair*2 + half) * HD + c0;
    f16x8 v = *(const f16x8*)p;
    float f[8], s = 0.f, q = 0.f;
    #pragma unroll
    for (int r = 0; r < 8; ++r){ f[r] = (float)v[r]; s += f[r]; q += f[r]*f[r]; }
    #pragma unroll
    for (int off = 16; off; off >>= 1){
      s += __shfl_xor(s, off);
      q += __shfl_xor(q, off);
    }
    float mu = s * (1.f / HD);
    float var = q * (1.f / HD) - mu * mu;
    float rs = rsqrtf(var + 1e-5f);
    f16x8 o;
    #pragma unroll
    for (int r = 0; r < 8; ++r){
      float y = (f[r] - mu) * rs * gw[r] + gb[r];
      o[r] = (f16)fmaxf(y, 0.f);
    }
    *(f16x8*)p = o;
  }
}

// ---------------- BatchNorm over axis0 (batch stats) + ReLU ------------------
__global__ __launch_bounds__(512)
void bn_relu(const float* __restrict__ part, const float* __restrict__ g,
             const float* __restrict__ b, float* __restrict__ z)
{
  __shared__ float lds[16];
  const int o = blockIdx.x, s = threadIdx.x, w = s >> 6;
  float y = 0.f;
  #pragma unroll
  for (int p = 0; p < 8; ++p) y += part[((size_t)p * 512 + o) * 512 + s];
  float su = y, q = y * y;
  #pragma unroll
  for (int off = 32; off; off >>= 1){
    su += __shfl_down(su, off);
    q  += __shfl_down(q, off);
  }
  if ((s & 63) == 0){ lds[w] = su; lds[8 + w] = q; }
  __syncthreads();
  float S = 0.f, Q = 0.f;
  #pragma unroll
  for (int i = 0; i < 8; ++i){ S += lds[i]; Q += lds[8 + i]; }
  float mu = S * (1.f / 512.f);
  float var = Q * (1.f / 512.f) - mu * mu;
  float zz = fmaxf((y - mu) * rsqrtf(var + 1e-5f) * g[o] + b[o], 0.f);
  z[(size_t)o * 512 + s] = zz;   // stored transposed [o][s]
}

// ---------------- fc3: out[s][c] = sum_o z[o][s]*w[c][o] + b[c] --------------
__global__ __launch_bounds__(256)
void fc3_k(const float* __restrict__ z, const float* __restrict__ w,
           const float* __restrict__ b, float* __restrict__ out)
{
  __shared__ float lds[12];
  const int s = blockIdx.x, tid = threadIdx.x, wv = tid >> 6;
  float a0 = 0.f, a1 = 0.f, a2 = 0.f;
  for (int o = tid; o < 512; o += 256){
    float zz = z[(size_t)o * 512 + s];
    a0 += zz * w[o];
    a1 += zz * w[512 + o];
    a2 += zz * w[1024 + o];
  }
  #pragma unroll
  for (int off = 32; off; off >>= 1){
    a0 += __shfl_down(a0, off);
    a1 += __shfl_down(a1, off);
    a2 += __shfl_down(a2, off);
  }
  if ((tid & 63) == 0){ lds[wv] = a0; lds[4 + wv] = a1; lds[8 + wv] = a2; }
  __syncthreads();
  if (tid == 0){
    out[s*3 + 0] = lds[0] + lds[1] + lds[2]  + lds[3]  + b[0];
    out[s*3 + 1] = lds[4] + lds[5] + lds[6]  + lds[7]  + b[1];
    out[s*3 + 2] = lds[8] + lds[9] + lds[10] + lds[11] + b[2];
  }
}

extern "C" void kernel_launch(void* const* d_in, const int* in_sizes, int n_in,
                              void* d_out, int out_size, void* d_ws, size_t ws_size,
                              hipStream_t stream)
{
  (void)in_sizes; (void)n_in; (void)out_size; (void)ws_size;
  const float* x    = (const float*)d_in[0];
  const float* wih0 = (const float*)d_in[1];
  const float* whh0 = (const float*)d_in[2];
  const float* bih0 = (const float*)d_in[3];
  const float* bhh0 = (const float*)d_in[4];
  const float* wih1 = (const float*)d_in[5];
  const float* whh1 = (const float*)d_in[6];
  const float* bih1 = (const float*)d_in[7];
  const float* bhh1 = (const float*)d_in[8];
  const float* lnw  = (const float*)d_in[9];
  const float* lnb  = (const float*)d_in[10];
  const float* fc2w = (const float*)d_in[11];
  // d_in[12] = fc2_b skipped: BN mean-centering cancels constant column bias.
  const float* bng  = (const float*)d_in[13];
  const float* bnb  = (const float*)d_in[14];
  const float* fc3w = (const float*)d_in[15];
  const float* fc3b = (const float*)d_in[16];
  float* out = (float*)d_out;

  char* ws = (char*)d_ws;
  size_t off = 0;
  auto alloc = [&](size_t bytes) -> void* {
    void* p = ws + off; off += (bytes + 255) & ~(size_t)255; return p;
  };
  f16* GI     = (f16*)alloc((size_t)SEQ*GI_TSTRIDE*2);  // 163.6 MB (permuted layout)
  f16* X16    = (f16*)alloc((size_t)SEQ*NB*64*2);       // 13.1 MB
  f16* WI0    = (f16*)alloc((size_t)768*64*2);
  f16* WH0    = (f16*)alloc((size_t)768*256*2);
  f16* WI1    = (f16*)alloc((size_t)768*256*2);
  f16* WH1    = (f16*)alloc((size_t)768*256*2);
  f16* HS0    = (f16*)alloc((size_t)SEQ*NB*256*2);      // 52.4 MB
  f16* HS1    = (f16*)alloc((size_t)SEQ*NB*256*2);      // 52.4 MB
  float* PART = (float*)alloc((size_t)8*512*512*4);     // 8.4 MB
  float* Z    = (float*)alloc((size_t)512*512*4);       // 1 MB (total ~292 MB)
  f16* FC2W   = GI;   // aliased: GI dead after gru1, FC2W converted after gru1

  cvt_f32_f16<<<2048,256,0,stream>>>(x,    X16,  SEQ*NB*64/4);
  cvt_f32_f16<<<64,  256,0,stream>>>(wih0, WI0,  768*64/4);
  cvt_f32_f16<<<192, 256,0,stream>>>(whh0, WH0,  768*256/4);
  cvt_f32_f16<<<192, 256,0,stream>>>(wih1, WI1,  768*256/4);
  cvt_f32_f16<<<192, 256,0,stream>>>(whh1, WH1,  768*256/4);

  dim3 g0(800, 6, 1);
  // gi0 = x @ w_ih0^T + b_ih0 (+ b_hh0 for r,z gates), permuted layout
  gemm_bt<0><<<g0, 256, 0, stream>>>(X16, WI0, GI, nullptr, bih0, bhh0, 64, GD, 64);
  gru_layer<<<NBLK, 1024, 0, stream>>>(WH0, bhh0, GI, HS0);
  gemm_bt<0><<<g0, 256, 0, stream>>>(HS0, WI1, GI, nullptr, bih1, bhh1, 256, GD, 256);
  gru_layer<<<NBLK, 1024, 0, stream>>>(WH1, bhh1, GI, HS1);
  // LayerNorm + ReLU in place -> hflat (fp16, layout already (512, 51200))
  ln_relu<<<3200, 256, 0, stream>>>(HS1, lnw, lnb);
  // fc2 weights converted now (GI dead), into GI-aliased buffer
  cvt_f32_f16<<<4096,256,0,stream>>>(fc2w, FC2W, 512*51200/4);
  dim3 g2(4, 4, 8);
  gemm_bt<1><<<g2, 256, 0, stream>>>(FC2W, HS1, nullptr, PART, nullptr, nullptr, 51200, 512, 6400);
  bn_relu<<<512, 512, 0, stream>>>(PART, bng, bnb, Z);
  fc3_k<<<512, 256, 0, stream>>>(Z, fc3w, fc3b, out);
}

// Round 9
// 3146.978 us; speedup vs baseline: 1.1776x; 1.1776x over previous
//
#include <hip/hip_runtime.h>
#include <stdint.h>

typedef _Float16 f16;
typedef _Float16 f16x4 __attribute__((ext_vector_type(4)));
typedef _Float16 f16x8 __attribute__((ext_vector_type(8)));
typedef float f32x4 __attribute__((ext_vector_type(4)));

#define SEQ 512
#define NB  200
#define HD  256
#define GD  768
#define BW  16
#define NBLK 13                    // ceil(200/16)
#define GI_TSTRIDE (NBLK*12288)    // halves per timestep = 159744
#define LOG2E 1.44269504f

__device__ __forceinline__ f32x4 mfma16(f16x8 a, f16x8 b, f32x4 c){
  return __builtin_amdgcn_mfma_f32_16x16x32_f16(a, b, c, 0, 0, 0);
}

// ---------------- fp32 -> fp16 convert ----------------
__global__ void cvt_f32_f16(const float* __restrict__ src, f16* __restrict__ dst, int n4){
  int i = blockIdx.x * blockDim.x + threadIdx.x;
  int stride = gridDim.x * blockDim.x;
  for (; i < n4; i += stride){
    float4 v = ((const float4*)src)[i];
    f16x4 o = { (f16)v.x, (f16)v.y, (f16)v.z, (f16)v.w };
    ((f16x4*)dst)[i] = o;
  }
}

// ---------------- GEMM: C[m][n] = sum_k A[m][k]*B[n][k] (both K-major) -------
// MODE 0: fp16 out into PERMUTED GI layout for the 16-wave gru reader.
//   Per (t, blk): 24KB region of 24 1KB chunks.
//   g -> q=g>>8, j=g&255, w=j>>4, jr=j&15, lane=(jr>>2)*16 + (b&15), rr=jr&3.
//   q<2 (r,z): idx = region + w*512 + lane*8 + q*4 + rr        (16B/lane)
//   q==2 (n):  idx = region + (16+(w>>1))*512 + (w&1)*256 + lane*4 + rr
//   bias1[g] (+bias2[g] for g<512: b_hh r,z folded in exactly).
// MODE 1: fp32 partials out[(z*512+row)*N+col].  grid (M/128, N/128, splits)
template<int MODE>
__global__ __launch_bounds__(256, 2)
void gemm_bt(const f16* __restrict__ A, const f16* __restrict__ B,
             f16* __restrict__ Cb, float* __restrict__ Cf,
             const float* __restrict__ bias1, const float* __restrict__ bias2,
             int K, int N, int klen)
{
  const int l  = threadIdx.x & 63;
  const int w  = threadIdx.x >> 6;
  const int lr = l & 15, lg = l >> 4;
  const int Mb = blockIdx.x * 128 + (w >> 1) * 64;
  const int Nb = blockIdx.y * 128 + (w & 1) * 64;
  const int kb = blockIdx.z * klen;

  const f16* Ap = A + (size_t)(Mb + lr) * K + kb + lg * 8;
  const f16* Bp = B + (size_t)(Nb + lr) * K + kb + lg * 8;

  f32x4 acc[4][4];
  #pragma unroll
  for (int i = 0; i < 4; ++i)
    #pragma unroll
    for (int j = 0; j < 4; ++j)
      acc[i][j] = (f32x4){0.f, 0.f, 0.f, 0.f};

  for (int k = 0; k < klen; k += 32){
    f16x8 af[4], bfr[4];
    #pragma unroll
    for (int i = 0; i < 4; ++i){
      af[i]  = *(const f16x8*)(Ap + (size_t)i * 16 * K + k);
      bfr[i] = *(const f16x8*)(Bp + (size_t)i * 16 * K + k);
    }
    #pragma unroll
    for (int i = 0; i < 4; ++i)
      #pragma unroll
      for (int j = 0; j < 4; ++j)
        acc[i][j] = mfma16(af[i], bfr[j], acc[i][j]);
  }

  if (MODE == 0){
    float bv[4];
    #pragma unroll
    for (int j = 0; j < 4; ++j){
      int g = Nb + j*16 + lr;
      bv[j] = bias1[g] + (g < 512 ? bias2[g] : 0.f);
    }
    #pragma unroll
    for (int i = 0; i < 4; ++i)
      #pragma unroll
      for (int r = 0; r < 4; ++r){
        int row = Mb + i*16 + lg*4 + r;
        int t = (int)(((uint64_t)(uint32_t)row * 167773u) >> 25);  // row/200 exact
        int b = row - t*200;
        int bblk = b >> 4, blr = b & 15;
        size_t region = ((size_t)t*NBLK + bblk) * 12288;
        #pragma unroll
        for (int j = 0; j < 4; ++j){
          int g = Nb + j*16 + lr;
          int q = g >> 8, jj = g & 255;
          int ww = jj >> 4, jr = jj & 15;
          int lane = (jr >> 2)*16 + blr;
          size_t idx;
          if (q < 2) idx = region + (size_t)ww*512 + lane*8 + q*4 + (jr & 3);
          else       idx = region + (size_t)(16 + (ww>>1))*512 + (ww&1)*256 + lane*4 + (jr & 3);
          Cb[idx] = (f16)(acc[i][j][r] + bv[j]);
        }
      }
  } else {
    #pragma unroll
    for (int i = 0; i < 4; ++i)
      #pragma unroll
      for (int j = 0; j < 4; ++j)
        #pragma unroll
        for (int r = 0; r < 4; ++r){
          int row = Mb + i*16 + lg*4 + r;
          int col = Nb + j*16 + lr;
          Cf[((size_t)blockIdx.z * 512 + row) * N + col] = acc[i][j][r];
        }
  }
}

// ---------------- persistent GRU layer: 13 blocks x 16 batch rows ------------
// 1024 threads = 16 waves = 4/SIMD. waves_per_eu(4,4) -> HARD 128-VGPR budget.
// Wave w owns hidden [16w,16w+16): weights = 24 f16x8 = 96 VGPR/lane, PINNED
// via opaque asm (remat impossible) and WITHIN budget (no spill) — the only
// winning cell of the {pinned?, within-budget?} matrix (r2-r8 post-mortems).
// MFMA-phase live set ~128: rz/nn gi reads moved AFTER the MFMA loop (safe:
// in-flight DMAs target buffer P^1). h double-buffered in LDS (swizzle
// c(b)=(b^(b>>2))&3); h_old in regs. gi prefetched one step ahead via
// global_load_lds (n chunks DMA'd by both reader waves, identical bytes).
__global__
__attribute__((amdgpu_flat_work_group_size(1024, 1024), amdgpu_waves_per_eu(4, 4)))
void gru_layer(const f16* __restrict__ whh, const float* __restrict__ bhh,
               const f16* __restrict__ gi, f16* __restrict__ hs)
{
  // [0,16384): h bufs (2x8192). [16384,65536): gi bufs (2x24576). pad -> 96KB
  // (1 block/CU).
  __shared__ __align__(16) unsigned char sm[16384 + 49152 + 32768];
  const int tid = threadIdx.x;
  const int w  = tid >> 6, l = tid & 63;
  const int lr = l & 15, lg = l >> 4;
  const int b0 = blockIdx.x * BW;
  const bool bval = (b0 + lr) < NB;

  ((int2*)sm)[tid] = make_int2(0,0);   // zero h buf0 (1024*8B = 8192)

  const int nchunk = 16 + (w >> 1);
  const f16* glane = gi + (size_t)blockIdx.x * 12288 + l*8;
#define DMA_GI(P) do { \
    __builtin_amdgcn_global_load_lds( \
        (const __attribute__((address_space(1))) void*)(glane + w*512), \
        (__attribute__((address_space(3))) void*)(sm + 16384 + (P)*24576 + w*1024), \
        16, 0, 0); \
    __builtin_amdgcn_global_load_lds( \
        (const __attribute__((address_space(1))) void*)(glane + nchunk*512), \
        (__attribute__((address_space(3))) void*)(sm + 16384 + (P)*24576 + nchunk*1024), \
        16, 0, 0); \
  } while(0)

  DMA_GI(0);   // t=0 prefetch

  // weight fragments: tile q covers gate rows q*256 + 16w + [0,16)
  // A-frag lane l: row = base + lr, k = kk*32 + lg*8 .. +7
  f16x8 wA[3][8];
  #pragma unroll
  for (int q = 0; q < 3; ++q)
    #pragma unroll
    for (int kk = 0; kk < 8; ++kk)
      wA[q][kk] = *(const f16x8*)(whh + (size_t)(q*256 + w*16 + lr)*256 + kk*32 + lg*8);

  // PIN the weights: opaque to the optimizer -> no remat; 96 regs <= budget
  // -> no spill. This is the load-once/use-512-times contract.
  #pragma unroll
  for (int q = 0; q < 3; ++q)
    #pragma unroll
    for (int kk = 0; kk < 8; ++kk)
      asm volatile("" : "+v"(wA[q][kk]));

  // n-gate bias for own rows j = 16w + lg*4 + r, packed f16
  f16x4 bnv;
  {
    float4 bv = *(const float4*)(bhh + 512 + w*16 + lg*4);
    bnv = (f16x4){(f16)bv.x,(f16)bv.y,(f16)bv.z,(f16)bv.w};
  }

  // LDS addressing. h element (k,b) at byte:
  //   (k>>5)*1024 + b*64 + (((k&31)*2) ^ (c(b)<<4)),  c(b) = (b ^ (b>>2)) & 3
  const int cswz = ((lr ^ (lr >> 2)) & 3) << 4;
  const int hrd  = lr*64 + ((lg*16) ^ cswz);                    // + kk*1024 + P*8192
  const int girz = 16384 + w*1024 + l*16;                       // + P*24576
  const int gin  = 16384 + nchunk*1024 + (w&1)*512 + l*8;       // + P*24576
  const int hwb  = (w>>1)*1024 + lr*64 + ((((w&1)*32) + lg*8) ^ cswz);  // + (P^1)*8192

  f16* hp = hs + (size_t)(b0 + lr)*HD + w*16 + lg*4;
  f16x4 hvp = (f16x4){(f16)0.f,(f16)0.f,(f16)0.f,(f16)0.f};

  asm volatile("s_waitcnt vmcnt(0)" ::: "memory");  // drain prologue
  __syncthreads();

#define GRUSTEP(P) do { \
    asm volatile("s_waitcnt vmcnt(0)" ::: "memory"); /* gi DMAs landed */ \
    f32x4 a0 = {0.f,0.f,0.f,0.f}, a1 = {0.f,0.f,0.f,0.f}; \
    f32x4 a2 = {(float)bnv[0],(float)bnv[1],(float)bnv[2],(float)bnv[3]}; \
    glane += GI_TSTRIDE; \
    DMA_GI((P)^1); \
    _Pragma("unroll") \
    for (int kk = 0; kk < 8; ++kk){ \
      f16x8 hf = *(const f16x8*)(sm + (P)*8192 + kk*1024 + hrd); \
      a0 = mfma16(wA[0][kk], hf, a0); \
      a1 = mfma16(wA[1][kk], hf, a1); \
      a2 = mfma16(wA[2][kk], hf, a2); \
    } \
    f16x8 rz = *(const f16x8*)(sm + (P)*24576 + girz); \
    f16x4 nn = *(const f16x4*)(sm + (P)*24576 + gin); \
    f16x4 hv; \
    _Pragma("unroll") \
    for (int r = 0; r < 4; ++r){ \
      float rg = __builtin_amdgcn_rcpf(1.f + __builtin_amdgcn_exp2f(-LOG2E*((float)rz[r] + a0[r]))); \
      float zg = __builtin_amdgcn_rcpf(1.f + __builtin_amdgcn_exp2f(-LOG2E*((float)rz[4+r] + a1[r]))); \
      float aa = (float)nn[r] + rg*a2[r]; \
      float ng = 2.f*__builtin_amdgcn_rcpf(1.f + __builtin_amdgcn_exp2f(-2.f*LOG2E*aa)) - 1.f; \
      float h  = ng + zg*((float)hvp[r] - ng); \
      hv[r] = (f16)h; \
    } \
    hvp = hv; \
    *(f16x4*)(sm + ((P)^1)*8192 + hwb) = hv; \
    if (bval) *(f16x4*)hp = hv; \
    hp += (size_t)NB*HD; \
    asm volatile("s_waitcnt lgkmcnt(0)" ::: "memory"); \
    __builtin_amdgcn_sched_barrier(0); \
    __builtin_amdgcn_s_barrier(); \
    __builtin_amdgcn_sched_barrier(0); \
  } while(0)

  for (int th = 0; th < SEQ/2; ++th){
    GRUSTEP(0);
    GRUSTEP(1);
  }
#undef GRUSTEP
#undef DMA_GI
}

// ---------------- LayerNorm(hidden) + ReLU, in place on fp16 [rows][256] -----
// Vectorized: each 64-lane wave handles 2 rows; lane reads f16x8.
__global__ __launch_bounds__(256)
void ln_relu(f16* __restrict__ hs, const float* __restrict__ lnw,
             const float* __restrict__ lnb)
{
  const int tid = threadIdx.x;
  const int wv = tid >> 6;           // 4 waves/block
  const int lane = tid & 63;
  const int half = lane >> 5;        // row within pair
  const int c0 = (lane & 31) * 8;
  float gw[8], gb[8];
  #pragma unroll
  for (int r = 0; r < 8; ++r){ gw[r] = lnw[c0 + r]; gb[r] = lnb[c0 + r]; }
  const int npairs = SEQ * NB / 2;   // 51200
  for (int pair = blockIdx.x * 4 + wv; pair < npairs; pair += gridDim.x * 4){
    f16* p = hs + (size_t)(pair*2 + half) * HD + c0;
    f16x8 v = *(const f16x8*)p;
    float f[8], s = 0.f, q = 0.f;
    #pragma unroll
    for (int r = 0; r < 8; ++r){ f[r] = (float)v[r]; s += f[r]; q += f[r]*f[r]; }
    #pragma unroll
    for (int off = 16; off; off >>= 1){
      s += __shfl_xor(s, off);
      q += __shfl_xor(q, off);
    }
    float mu = s * (1.f / HD);
    float var = q * (1.f / HD) - mu * mu;
    float rs = rsqrtf(var + 1e-5f);
    f16x8 o;
    #pragma unroll
    for (int r = 0; r < 8; ++r){
      float y = (f[r] - mu) * rs * gw[r] + gb[r];
      o[r] = (f16)fmaxf(y, 0.f);
    }
    *(f16x8*)p = o;
  }
}

// ---------------- BatchNorm over axis0 (batch stats) + ReLU ------------------
__global__ __launch_bounds__(512)
void bn_relu(const float* __restrict__ part, const float* __restrict__ g,
             const float* __restrict__ b, float* __restrict__ z)
{
  __shared__ float lds[16];
  const int o = blockIdx.x, s = threadIdx.x, w = s >> 6;
  float y = 0.f;
  #pragma unroll
  for (int p = 0; p < 8; ++p) y += part[((size_t)p * 512 + o) * 512 + s];
  float su = y, q = y * y;
  #pragma unroll
  for (int off = 32; off; off >>= 1){
    su += __shfl_down(su, off);
    q  += __shfl_down(q, off);
  }
  if ((s & 63) == 0){ lds[w] = su; lds[8 + w] = q; }
  __syncthreads();
  float S = 0.f, Q = 0.f;
  #pragma unroll
  for (int i = 0; i < 8; ++i){ S += lds[i]; Q += lds[8 + i]; }
  float mu = S * (1.f / 512.f);
  float var = Q * (1.f / 512.f) - mu * mu;
  float zz = fmaxf((y - mu) * rsqrtf(var + 1e-5f) * g[o] + b[o], 0.f);
  z[(size_t)o * 512 + s] = zz;   // stored transposed [o][s]
}

// ---------------- fc3: out[s][c] = sum_o z[o][s]*w[c][o] + b[c] --------------
__global__ __launch_bounds__(256)
void fc3_k(const float* __restrict__ z, const float* __restrict__ w,
           const float* __restrict__ b, float* __restrict__ out)
{
  __shared__ float lds[12];
  const int s = blockIdx.x, tid = threadIdx.x, wv = tid >> 6;
  float a0 = 0.f, a1 = 0.f, a2 = 0.f;
  for (int o = tid; o < 512; o += 256){
    float zz = z[(size_t)o * 512 + s];
    a0 += zz * w[o];
    a1 += zz * w[512 + o];
    a2 += zz * w[1024 + o];
  }
  #pragma unroll
  for (int off = 32; off; off >>= 1){
    a0 += __shfl_down(a0, off);
    a1 += __shfl_down(a1, off);
    a2 += __shfl_down(a2, off);
  }
  if ((tid & 63) == 0){ lds[wv] = a0; lds[4 + wv] = a1; lds[8 + wv] = a2; }
  __syncthreads();
  if (tid == 0){
    out[s*3 + 0] = lds[0] + lds[1] + lds[2]  + lds[3]  + b[0];
    out[s*3 + 1] = lds[4] + lds[5] + lds[6]  + lds[7]  + b[1];
    out[s*3 + 2] = lds[8] + lds[9] + lds[10] + lds[11] + b[2];
  }
}

extern "C" void kernel_launch(void* const* d_in, const int* in_sizes, int n_in,
                              void* d_out, int out_size, void* d_ws, size_t ws_size,
                              hipStream_t stream)
{
  (void)in_sizes; (void)n_in; (void)out_size; (void)ws_size;
  const float* x    = (const float*)d_in[0];
  const float* wih0 = (const float*)d_in[1];
  const float* whh0 = (const float*)d_in[2];
  const float* bih0 = (const float*)d_in[3];
  const float* bhh0 = (const float*)d_in[4];
  const float* wih1 = (const float*)d_in[5];
  const float* whh1 = (const float*)d_in[6];
  const float* bih1 = (const float*)d_in[7];
  const float* bhh1 = (const float*)d_in[8];
  const float* lnw  = (const float*)d_in[9];
  const float* lnb  = (const float*)d_in[10];
  const float* fc2w = (const float*)d_in[11];
  // d_in[12] = fc2_b skipped: BN mean-centering cancels constant column bias.
  const float* bng  = (const float*)d_in[13];
  const float* bnb  = (const float*)d_in[14];
  const float* fc3w = (const float*)d_in[15];
  const float* fc3b = (const float*)d_in[16];
  float* out = (float*)d_out;

  char* ws = (char*)d_ws;
  size_t off = 0;
  auto alloc = [&](size_t bytes) -> void* {
    void* p = ws + off; off += (bytes + 255) & ~(size_t)255; return p;
  };
  f16* GI     = (f16*)alloc((size_t)SEQ*GI_TSTRIDE*2);  // 163.6 MB (permuted layout)
  f16* X16    = (f16*)alloc((size_t)SEQ*NB*64*2);       // 13.1 MB
  f16* WI0    = (f16*)alloc((size_t)768*64*2);
  f16* WH0    = (f16*)alloc((size_t)768*256*2);
  f16* WI1    = (f16*)alloc((size_t)768*256*2);
  f16* WH1    = (f16*)alloc((size_t)768*256*2);
  f16* HS0    = (f16*)alloc((size_t)SEQ*NB*256*2);      // 52.4 MB
  f16* HS1    = (f16*)alloc((size_t)SEQ*NB*256*2);      // 52.4 MB
  float* PART = (float*)alloc((size_t)8*512*512*4);     // 8.4 MB
  float* Z    = (float*)alloc((size_t)512*512*4);       // 1 MB (total ~292 MB)
  f16* FC2W   = GI;   // aliased: GI dead after gru1, FC2W converted after gru1

  cvt_f32_f16<<<2048,256,0,stream>>>(x,    X16,  SEQ*NB*64/4);
  cvt_f32_f16<<<64,  256,0,stream>>>(wih0, WI0,  768*64/4);
  cvt_f32_f16<<<192, 256,0,stream>>>(whh0, WH0,  768*256/4);
  cvt_f32_f16<<<192, 256,0,stream>>>(wih1, WI1,  768*256/4);
  cvt_f32_f16<<<192, 256,0,stream>>>(whh1, WH1,  768*256/4);

  dim3 g0(800, 6, 1);
  // gi0 = x @ w_ih0^T + b_ih0 (+ b_hh0 for r,z gates), permuted layout
  gemm_bt<0><<<g0, 256, 0, stream>>>(X16, WI0, GI, nullptr, bih0, bhh0, 64, GD, 64);
  gru_layer<<<NBLK, 1024, 0, stream>>>(WH0, bhh0, GI, HS0);
  gemm_bt<0><<<g0, 256, 0, stream>>>(HS0, WI1, GI, nullptr, bih1, bhh1, 256, GD, 256);
  gru_layer<<<NBLK, 1024, 0, stream>>>(WH1, bhh1, GI, HS1);
  // LayerNorm + ReLU in place -> hflat (fp16, layout already (512, 51200))
  ln_relu<<<3200, 256, 0, stream>>>(HS1, lnw, lnb);
  // fc2 weights converted now (GI dead), into GI-aliased buffer
  cvt_f32_f16<<<4096,256,0,stream>>>(fc2w, FC2W, 512*51200/4);
  dim3 g2(4, 4, 8);
  gemm_bt<1><<<g2, 256, 0, stream>>>(FC2W, HS1, nullptr, PART, nullptr, nullptr, 51200, 512, 6400);
  bn_relu<<<512, 512, 0, stream>>>(PART, bng, bnb, Z);
  fc3_k<<<512, 256, 0, stream>>>(Z, fc3w, fc3b, out);
}